// Round 2
// baseline (173.892 us; speedup 1.0000x reference)
//
#include <hip/hip_runtime.h>
#include <math.h>

#define TT 512
#define DD 512
#define SCALE 0.125f  // 1/sqrt(64)

// ---------------------------------------------------------------------------
// ws layout (floats):
//   xT   [512][512]   @ 0         xT[d][t]  = x[t][d]
//   WT   [512][1536]  @ 262144    WT[d][o'] = W{q,k,v}[o][d], o' = m*512+o
//   WoT  [512][512]   @ 1048576   WoT[d][o] = Wo[o][d]
//   qkv  [1536][512]  @ 1310720   rows 0-511 q, 512-1023 k(scaled), 1024-1535 v
//   att  [512][512]   @ 2097152   att[d][t]
// ---------------------------------------------------------------------------
#define OFF_XT   0
#define OFF_WT   262144
#define OFF_WOT  1048576
#define OFF_QKV  1310720
#define OFF_ATT  2097152

// ---------------------------------------------------------------------------
// Kernel 1: transpose/pack.  z=0: x->xT, z=1..3: Wq/Wk/Wv -> WT, z=4: Wo->WoT
// ---------------------------------------------------------------------------
__global__ __launch_bounds__(256) void transpose_pack(
    const float* __restrict__ x,  const float* __restrict__ Wq,
    const float* __restrict__ Wk, const float* __restrict__ Wv,
    const float* __restrict__ Wo, float* __restrict__ ws)
{
    __shared__ float tile[32][33];
    const int z = blockIdx.z;
    const float* src; float* dst; int ostride, ocol;
    if (z == 0)      { src = x;  dst = ws + OFF_XT;  ostride = 512;  ocol = 0; }
    else if (z == 4) { src = Wo; dst = ws + OFF_WOT; ostride = 512;  ocol = 0; }
    else { src = (z == 1) ? Wq : (z == 2) ? Wk : Wv;
           dst = ws + OFF_WT; ostride = 1536; ocol = (z - 1) * 512; }

    const int r0 = blockIdx.y * 32, c0 = blockIdx.x * 32;
    const int tx = threadIdx.x, ty = threadIdx.y;  // 32 x 8
    #pragma unroll
    for (int i = 0; i < 32; i += 8)
        tile[ty + i][tx] = src[(r0 + ty + i) * 512 + c0 + tx];
    __syncthreads();
    #pragma unroll
    for (int i = 0; i < 32; i += 8)
        dst[(c0 + ty + i) * ostride + ocol + r0 + tx] = tile[tx][ty + i];
}

// ---------------------------------------------------------------------------
// Kernel 2: QKV projection.  qkv[o',t] = sum_d WT[d][o'] * xT[d][t]
// Wave = 8 o-rows x 64 t-lanes. W-chunk is wave-uniform -> s_load path.
// Block 128 thr = 2 waves (o-stacked). Grid (8 t-tiles, 96 o-tiles) = 768.
// ---------------------------------------------------------------------------
__global__ __launch_bounds__(128) void qkv_gemm(
    const float* __restrict__ xT, const float* __restrict__ WT,
    float* __restrict__ qkv)
{
    const int lane = threadIdx.x & 63;
    const int wv   = __builtin_amdgcn_readfirstlane(threadIdx.x >> 6);  // 0..1
    const int t    = blockIdx.x * 64 + lane;
    const int o0   = blockIdx.y * 16 + wv * 8;

    const float* __restrict__ wp = WT + o0;   // + d*1536, wave-uniform
    const float* __restrict__ xp = xT + t;    // + d*512, per-lane coalesced

    float acc[8] = {0.f, 0.f, 0.f, 0.f, 0.f, 0.f, 0.f, 0.f};

    #pragma unroll 4
    for (int d = 0; d < 512; ++d) {
        const float xv = xp[d * 512];
        const float4 w0 = *(const float4*)(wp + d * 1536);
        const float4 w1 = *(const float4*)(wp + d * 1536 + 4);
        acc[0] = fmaf(w0.x, xv, acc[0]);
        acc[1] = fmaf(w0.y, xv, acc[1]);
        acc[2] = fmaf(w0.z, xv, acc[2]);
        acc[3] = fmaf(w0.w, xv, acc[3]);
        acc[4] = fmaf(w1.x, xv, acc[4]);
        acc[5] = fmaf(w1.y, xv, acc[5]);
        acc[6] = fmaf(w1.z, xv, acc[6]);
        acc[7] = fmaf(w1.w, xv, acc[7]);
    }
    #pragma unroll
    for (int r = 0; r < 8; ++r)
        qkv[(o0 + r) * 512 + t] = acc[r];
}

// ---------------------------------------------------------------------------
// Kernel 3: RoPE in place on q,k rows of qkv; fold SCALE into k.
// rotate_half pairs head h with h+4 (channels o and o+256).
// ---------------------------------------------------------------------------
__global__ __launch_bounds__(256) void rope_scale(float* __restrict__ qkv)
{
    const int idx = blockIdx.x * 256 + threadIdx.x;  // 0 .. 131071
    const int t = idx & 511;
    const int c = (idx >> 9) & 63;
    const int h = idx >> 15;        // 0..3
    const int f = c & 31;

    const float inv_freq = powf(10000.0f, -(float)f * (1.0f / 32.0f));
    float sn, cs;
    sincosf((float)t * inv_freq, &sn, &cs);

    const int lo = h * 64 + c, hi = (h + 4) * 64 + c;
    float* __restrict__ q = qkv;
    float* __restrict__ k = qkv + 512 * 512;

    const float qlo = q[lo * 512 + t], qhi = q[hi * 512 + t];
    q[lo * 512 + t] = qlo * cs - qhi * sn;
    q[hi * 512 + t] = qhi * cs + qlo * sn;

    const float klo = k[lo * 512 + t], khi = k[hi * 512 + t];
    k[lo * 512 + t] = (klo * cs - khi * sn) * SCALE;
    k[hi * 512 + t] = (khi * cs + klo * sn) * SCALE;
}

// ---------------------------------------------------------------------------
// Kernel 4: per-channel scalar causal attention.
// s_ij = q_i * a_j (a = scaled roped k). Row max from prefix max/min scan.
// Inner loop: wave-uniform float4 loads of a,v (s_load path) — no LDS.
// ---------------------------------------------------------------------------
__global__ __launch_bounds__(512) void attn(
    const float* __restrict__ qkv, float* __restrict__ att)
{
    const int ch = blockIdx.x;
    const int i  = threadIdx.x;

    const float* __restrict__ qg = qkv + ch * 512;
    const float* __restrict__ kg = qkv + 262144 + ch * 512;
    const float* __restrict__ vg = qkv + 524288 + ch * 512;

    __shared__ float pmx[TT];
    __shared__ float pmn[TT];

    const float av = kg[i];
    pmx[i] = av;
    pmn[i] = av;
    __syncthreads();

    // inclusive prefix max/min (Hillis-Steele)
    float mx = av, mn = av;
    for (int off = 1; off < TT; off <<= 1) {
        const float omx = (i >= off) ? pmx[i - off] : -INFINITY;
        const float omn = (i >= off) ? pmn[i - off] :  INFINITY;
        __syncthreads();
        mx = fmaxf(mx, omx);
        mn = fminf(mn, omn);
        pmx[i] = mx;
        pmn[i] = mn;
        __syncthreads();
    }

    const float qi = qg[i];
    const float m  = (qi >= 0.f) ? qi * mx : qi * mn;  // exact rowmax
    const float nm = -m;

    float l = 0.f, acc = 0.f;
    const int jend = __builtin_amdgcn_readfirstlane(i & ~63);  // wave-uniform

    #pragma unroll 2
    for (int j = 0; j < jend; j += 4) {          // unmasked: j < i for all lanes
        const float4 a4 = *(const float4*)(kg + j);
        const float4 v4 = *(const float4*)(vg + j);
        float e;
        e = __expf(fmaf(qi, a4.x, nm)); l += e; acc = fmaf(e, v4.x, acc);
        e = __expf(fmaf(qi, a4.y, nm)); l += e; acc = fmaf(e, v4.y, acc);
        e = __expf(fmaf(qi, a4.z, nm)); l += e; acc = fmaf(e, v4.z, acc);
        e = __expf(fmaf(qi, a4.w, nm)); l += e; acc = fmaf(e, v4.w, acc);
    }
    #pragma unroll
    for (int u = 0; u < 64; u += 4) {            // masked tail (this wave's 64)
        const int j = jend + u;
        const float4 a4 = *(const float4*)(kg + j);
        const float4 v4 = *(const float4*)(vg + j);
        float e;
        e = (j + 0 <= i) ? __expf(fmaf(qi, a4.x, nm)) : 0.f; l += e; acc = fmaf(e, v4.x, acc);
        e = (j + 1 <= i) ? __expf(fmaf(qi, a4.y, nm)) : 0.f; l += e; acc = fmaf(e, v4.y, acc);
        e = (j + 2 <= i) ? __expf(fmaf(qi, a4.z, nm)) : 0.f; l += e; acc = fmaf(e, v4.z, acc);
        e = (j + 3 <= i) ? __expf(fmaf(qi, a4.w, nm)) : 0.f; l += e; acc = fmaf(e, v4.w, acc);
    }
    att[ch * 512 + i] = acc / l;
}

// ---------------------------------------------------------------------------
// Kernel 5: output projection.  out[t][o] = sum_d WoT[d][o] * att[d][t]
// Wave = 4 t-rows x 64 o-lanes; att t-chunk is wave-uniform (s_load path).
// Block 256 thr = 4 waves (t-stacked). Grid (8 o-tiles, 32 t-tiles) = 256.
// ---------------------------------------------------------------------------
__global__ __launch_bounds__(256) void outproj(
    const float* __restrict__ att, const float* __restrict__ WoT,
    float* __restrict__ out)
{
    const int lane = threadIdx.x & 63;
    const int wv   = __builtin_amdgcn_readfirstlane(threadIdx.x >> 6);  // 0..3
    const int o    = blockIdx.x * 64 + lane;
    const int t0   = blockIdx.y * 16 + wv * 4;

    const float* __restrict__ ap = att + t0;   // + d*512, wave-uniform float4
    const float* __restrict__ wp = WoT + o;    // + d*512, per-lane coalesced

    float acc[4] = {0.f, 0.f, 0.f, 0.f};

    #pragma unroll 4
    for (int d = 0; d < 512; ++d) {
        const float w  = wp[d * 512];
        const float4 a4 = *(const float4*)(ap + d * 512);
        acc[0] = fmaf(a4.x, w, acc[0]);
        acc[1] = fmaf(a4.y, w, acc[1]);
        acc[2] = fmaf(a4.z, w, acc[2]);
        acc[3] = fmaf(a4.w, w, acc[3]);
    }
    #pragma unroll
    for (int r = 0; r < 4; ++r)
        out[(t0 + r) * 512 + o] = acc[r];
}

// ---------------------------------------------------------------------------
extern "C" void kernel_launch(void* const* d_in, const int* in_sizes, int n_in,
                              void* d_out, int out_size, void* d_ws, size_t ws_size,
                              hipStream_t stream)
{
    const float* x  = (const float*)d_in[0];
    const float* Wq = (const float*)d_in[1];
    const float* Wk = (const float*)d_in[2];
    const float* Wv = (const float*)d_in[3];
    const float* Wo = (const float*)d_in[4];
    float* out = (float*)d_out;
    float* ws  = (float*)d_ws;

    float* xT  = ws + OFF_XT;
    float* WT  = ws + OFF_WT;
    float* WoT = ws + OFF_WOT;
    float* qkv = ws + OFF_QKV;
    float* att = ws + OFF_ATT;

    transpose_pack<<<dim3(16, 16, 5), dim3(32, 8), 0, stream>>>(x, Wq, Wk, Wv, Wo, ws);
    qkv_gemm<<<dim3(8, 96), 128, 0, stream>>>(xT, WT, qkv);
    rope_scale<<<512, 256, 0, stream>>>(qkv);
    attn<<<512, 512, 0, stream>>>(qkv, att);
    outproj<<<dim3(8, 32), 256, 0, stream>>>(att, WoT, out);
}

// Round 3
// 102.578 us; speedup vs baseline: 1.6952x; 1.6952x over previous
//
#include <hip/hip_runtime.h>
#include <math.h>

// ---------------------------------------------------------------------------
// Types for MFMA fragments (guide §3: bf16 16x16x32 -> 8 bf16 in, 4 f32 out)
// ---------------------------------------------------------------------------
typedef __attribute__((ext_vector_type(8))) short short8;
typedef __attribute__((ext_vector_type(4))) float floatx4;

__device__ __forceinline__ unsigned short f2bf(float f) {
    unsigned int u = __builtin_bit_cast(unsigned int, f);
    u += 0x7FFFu + ((u >> 16) & 1u);   // round-to-nearest-even
    return (unsigned short)(u >> 16);
}

// ---------------------------------------------------------------------------
// ws layout:
//   Wallb bf16 [1536][512]  (Wq rows 0-511, Wk 512-1023, Wv 1024-1535)
//   xb    bf16 [512][512]   (x, [t][d])
//   Wob   bf16 [512][512]   ([o][d])
//   attTb bf16 [512][512]   ([t][d])
//   qkvf  f32  [1536][512]  ([o'][t]; q rows 0-511, k 512-1023, v 1024-1535)
//   attf  f32  [512][512]   ([d][t])
// ---------------------------------------------------------------------------

// ---------------------------------------------------------------------------
// Kernel 1: fp32 -> bf16 conversion for x, Wq, Wk, Wv, Wo (pure elementwise).
// grid (256, 5), block 256; each thread converts 4 elements.
// ---------------------------------------------------------------------------
__global__ __launch_bounds__(256) void cvt_bf16(
    const float* __restrict__ x,  const float* __restrict__ Wq,
    const float* __restrict__ Wk, const float* __restrict__ Wv,
    const float* __restrict__ Wo, unsigned short* __restrict__ Wallb,
    unsigned short* __restrict__ xb, unsigned short* __restrict__ Wob)
{
    const float* src; unsigned short* dst;
    switch (blockIdx.y) {
        case 0: src = Wq; dst = Wallb;          break;
        case 1: src = Wk; dst = Wallb + 262144; break;
        case 2: src = Wv; dst = Wallb + 524288; break;
        case 3: src = x;  dst = xb;             break;
        default: src = Wo; dst = Wob;           break;
    }
    const int i4 = (blockIdx.x * 256 + threadIdx.x) * 4;
    const float4 v = *(const float4*)(src + i4);
    ushort4 o;
    o.x = f2bf(v.x); o.y = f2bf(v.y); o.z = f2bf(v.z); o.w = f2bf(v.w);
    *(ushort4*)(dst + i4) = o;
}

// ---------------------------------------------------------------------------
// Kernel 2/5: bf16 MFMA GEMM, C[m][n] = sum_k A[m][k]*B[n][k] (both k-contig).
// K = 512 fixed, ldc = 512 fixed. Block 256 thr = 4 waves; 64x64 block tile;
// wave tile 32x32 = 2x2 mfma_f32_16x16x32_bf16 tiles. BK=64, single-buffered,
// global_load_lds width 16, XOR-swizzled k-chunks to avoid bank conflicts.
// ---------------------------------------------------------------------------
__global__ __launch_bounds__(256) void gemm_bt(
    const unsigned short* __restrict__ A,   // [M][512] bf16
    const unsigned short* __restrict__ B,   // [N][512] bf16
    float* __restrict__ C)                  // [M][512] f32
{
    __shared__ unsigned short As[64 * 64];
    __shared__ unsigned short Bs[64 * 64];

    const int tid  = threadIdx.x;
    const int lane = tid & 63;
    const int w    = tid >> 6;            // wave 0..3
    const int m0   = blockIdx.y * 64;
    const int n0   = blockIdx.x * 64;
    const int wm   = (w >> 1) * 32;
    const int wn   = (w & 1) * 32;

    const int srow8 = w * 8 + (lane >> 3);  // staging row within 32-row round
    const int c8    = lane & 7;             // 16B chunk index within 64-k row

    floatx4 acc[2][2] = {{{0.f,0.f,0.f,0.f},{0.f,0.f,0.f,0.f}},
                         {{0.f,0.f,0.f,0.f},{0.f,0.f,0.f,0.f}}};

    const int quad = lane >> 4;
    const int l15  = lane & 15;

    for (int kc = 0; kc < 512; kc += 64) {
        #pragma unroll
        for (int rr = 0; rr < 2; ++rr) {
            const int row  = rr * 32 + srow8;           // 0..63
            const int gcol = kc + ((c8 ^ (row & 7)) * 8);
            const unsigned short* ga = A + (m0 + row) * 512 + gcol;
            const unsigned short* gb = B + (n0 + row) * 512 + gcol;
            __builtin_amdgcn_global_load_lds(
                (const __attribute__((address_space(1))) void*)ga,
                (__attribute__((address_space(3))) void*)&As[(rr * 32 + w * 8) * 64],
                16, 0, 0);
            __builtin_amdgcn_global_load_lds(
                (const __attribute__((address_space(1))) void*)gb,
                (__attribute__((address_space(3))) void*)&Bs[(rr * 32 + w * 8) * 64],
                16, 0, 0);
        }
        __syncthreads();

        #pragma unroll
        for (int ks = 0; ks < 2; ++ks) {
            const int cIdx = ks * 4 + quad;             // 16B chunk 0..7
            short8 a[2], b[2];
            #pragma unroll
            for (int mt = 0; mt < 2; ++mt) {
                const int row = wm + mt * 16 + l15;
                a[mt] = *(const short8*)&As[row * 64 + ((cIdx ^ (row & 7)) * 8)];
            }
            #pragma unroll
            for (int nt = 0; nt < 2; ++nt) {
                const int row = wn + nt * 16 + l15;
                b[nt] = *(const short8*)&Bs[row * 64 + ((cIdx ^ (row & 7)) * 8)];
            }
            #pragma unroll
            for (int mt = 0; mt < 2; ++mt)
                #pragma unroll
                for (int nt = 0; nt < 2; ++nt)
                    acc[mt][nt] = __builtin_amdgcn_mfma_f32_16x16x32_bf16(
                        a[mt], b[nt], acc[mt][nt], 0, 0, 0);
        }
        __syncthreads();
    }

    // C/D layout (m89-verified): row = quad*4 + reg, col = lane&15
    #pragma unroll
    for (int mt = 0; mt < 2; ++mt)
        #pragma unroll
        for (int nt = 0; nt < 2; ++nt) {
            const int grow = m0 + wm + mt * 16 + quad * 4;
            const int gcol = n0 + wn + nt * 16 + l15;
            #pragma unroll
            for (int r = 0; r < 4; ++r)
                C[(grow + r) * 512 + gcol] = acc[mt][nt][r];
        }
}

// ---------------------------------------------------------------------------
// Kernel 3: fused RoPE + per-channel scalar causal attention (fp32).
// Block = one channel ch (512 blocks), 512 threads (one per query i).
// RoPE pairs ch with ch^256 (heads split 0-3 / 4-7). Scale 1/8 folded into k.
// No max-subtraction: |q*k/8| <~ 3, exp cannot overflow; same math as ref.
// ---------------------------------------------------------------------------
__global__ __launch_bounds__(512) void attn_rope(
    const float* __restrict__ qkv, float* __restrict__ att)
{
    const int ch = blockIdx.x;
    const int i  = threadIdx.x;
    const int c  = ch & 63;
    const int p  = ch ^ 256;
    const float sgn = (ch < 256) ? -1.f : 1.f;

    __shared__ float ks_[512];
    __shared__ float vs_[512];

    const float* __restrict__ qg = qkv;
    const float* __restrict__ kg = qkv + 262144;
    const float* __restrict__ vg = qkv + 524288;

    const float inv_freq = powf(10000.f, -(float)(c & 31) * (1.f / 32.f));
    float sn, cs;
    sincosf((float)i * inv_freq, &sn, &cs);

    const float kv = kg[ch * 512 + i], kpv = kg[p * 512 + i];
    ks_[i] = (kv * cs + sgn * kpv * sn) * 0.125f;
    vs_[i] = vg[ch * 512 + i];
    const float qv = qg[ch * 512 + i], qpv = qg[p * 512 + i];
    const float qi = qv * cs + sgn * qpv * sn;
    __syncthreads();

    float l = 0.f, acc = 0.f;
    const int jend = i & ~63;   // wave-uniform

    #pragma unroll 2
    for (int j = 0; j < jend; j += 4) {     // all j < i here: unmasked
        const float4 a4 = *(const float4*)&ks_[j];
        const float4 v4 = *(const float4*)&vs_[j];
        float e;
        e = __expf(qi * a4.x); l += e; acc = fmaf(e, v4.x, acc);
        e = __expf(qi * a4.y); l += e; acc = fmaf(e, v4.y, acc);
        e = __expf(qi * a4.z); l += e; acc = fmaf(e, v4.z, acc);
        e = __expf(qi * a4.w); l += e; acc = fmaf(e, v4.w, acc);
    }
    #pragma unroll
    for (int u = 0; u < 64; u += 4) {       // masked tail (this wave's 64 j's)
        const int j = jend + u;
        const float4 a4 = *(const float4*)&ks_[j];
        const float4 v4 = *(const float4*)&vs_[j];
        float e;
        e = (j + 0 <= i) ? __expf(qi * a4.x) : 0.f; l += e; acc = fmaf(e, v4.x, acc);
        e = (j + 1 <= i) ? __expf(qi * a4.y) : 0.f; l += e; acc = fmaf(e, v4.y, acc);
        e = (j + 2 <= i) ? __expf(qi * a4.z) : 0.f; l += e; acc = fmaf(e, v4.z, acc);
        e = (j + 3 <= i) ? __expf(qi * a4.w) : 0.f; l += e; acc = fmaf(e, v4.w, acc);
    }
    att[ch * 512 + i] = acc / l;
}

// ---------------------------------------------------------------------------
// Kernel 4: att [d][t] f32  ->  attTb [t][d] bf16 (LDS 32x32 transpose).
// ---------------------------------------------------------------------------
__global__ __launch_bounds__(256) void attT_cvt(
    const float* __restrict__ att, unsigned short* __restrict__ attTb)
{
    __shared__ float tile[32][33];
    const int d0 = blockIdx.y * 32, t0 = blockIdx.x * 32;
    const int tx = threadIdx.x, ty = threadIdx.y;   // 32 x 8
    #pragma unroll
    for (int i = 0; i < 32; i += 8)
        tile[ty + i][tx] = att[(d0 + ty + i) * 512 + t0 + tx];
    __syncthreads();
    #pragma unroll
    for (int i = 0; i < 32; i += 8)
        attTb[(t0 + ty + i) * 512 + d0 + tx] = f2bf(tile[tx][ty + i]);
}

// ---------------------------------------------------------------------------
extern "C" void kernel_launch(void* const* d_in, const int* in_sizes, int n_in,
                              void* d_out, int out_size, void* d_ws, size_t ws_size,
                              hipStream_t stream)
{
    const float* x  = (const float*)d_in[0];
    const float* Wq = (const float*)d_in[1];
    const float* Wk = (const float*)d_in[2];
    const float* Wv = (const float*)d_in[3];
    const float* Wo = (const float*)d_in[4];
    float* out = (float*)d_out;

    unsigned short* Wallb = (unsigned short*)d_ws;        // 786432 bf16
    unsigned short* xb    = Wallb + 786432;               // 262144
    unsigned short* Wob   = xb + 262144;                  // 262144
    unsigned short* attTb = Wob + 262144;                 // 262144
    float* qkvf = (float*)(attTb + 262144);               // 786432 f32
    float* attf = qkvf + 786432;                          // 262144 f32

    cvt_bf16<<<dim3(256, 5), 256, 0, stream>>>(x, Wq, Wk, Wv, Wo, Wallb, xb, Wob);
    // qkv: C[o'][t] = sum_d Wall[o'][d] * x[t][d]   (M=1536, N=512)
    gemm_bt<<<dim3(8, 24), 256, 0, stream>>>(Wallb, xb, qkvf);
    attn_rope<<<512, 512, 0, stream>>>(qkvf, attf);
    attT_cvt<<<dim3(16, 16), dim3(32, 8), 0, stream>>>(attf, attTb);
    // out: C[t][o] = sum_d attT[t][d] * Wo[o][d]    (M=512, N=512)
    gemm_bt<<<dim3(8, 8), 256, 0, stream>>>(attTb, Wob, out);
}